// Round 7
// baseline (339.305 us; speedup 1.0000x reference)
//
#include <hip/hip_runtime.h>
#include <hip/hip_bf16.h>

// EfficientAttention: B=4, N=8192, C=384, H=6, D=64
// Round 7: proj de-serialized — direct global->register A-frags (A_s deleted),
// direct scattered q stores (qbuf deleted), XOR-swizzled W_s (49152 B -> 3
// blocks/CU), zero barriers in the sub loop. kv reduce overlays W_s in 2 halves.

#define B 4
#define N 8192
#define C 384
#define H 6
#define D 64
#define BH (B * H)   // 24
#define BN (B * N)   // 32768

typedef __attribute__((ext_vector_type(8))) short short8;
typedef __attribute__((ext_vector_type(4))) float f32x4;

__device__ inline unsigned short f2bf(float f) {
    unsigned int u = __float_as_uint(f);
    unsigned int r = (u + 0x7fff + ((u >> 16) & 1)) >> 16;   // RNE
    return (unsigned short)r;
}
__device__ inline float bf2f(unsigned short h) {
    return __uint_as_float(((unsigned int)h) << 16);
}

// ---------------------------------------------------------------------------
// Kernel 0: transpose + hi/lo-split the three weight sets.
// Whi/Wlo layout: [mat][h][e][d] bf16, value = W[d][e]  (B-operand rows = e).
// ---------------------------------------------------------------------------
__global__ void wprep(const float* __restrict__ Wq, const float* __restrict__ Wk,
                      const float* __restrict__ Wv,
                      unsigned short* __restrict__ Whi, unsigned short* __restrict__ Wlo)
{
    __shared__ float tmp[64][65];
    const int m = blockIdx.x / H;
    const int h = blockIdx.x % H;
    const float* in = (m == 0 ? Wq : m == 1 ? Wk : Wv) + h * 64 * 64;
    const int t = threadIdx.x;
    for (int d = 0; d < 64; ++d) tmp[d][t] = in[d * 64 + t];   // tmp[d][e]
    __syncthreads();
    const size_t base = ((size_t)(m * H + h)) * 64 * 64;
    for (int e = 0; e < 64; ++e) {
        float v = tmp[t][e];                    // W[d=t][e] -> out[e][d=t]
        unsigned short hb = f2bf(v);
        Whi[base + e * 64 + t] = hb;
        Wlo[base + e * 64 + t] = f2bf(v - bf2f(hb));
    }
}

// ---------------------------------------------------------------------------
// Kernel 1 (MFMA): per-head QKV projection + q softmax + fused kv-partial
// accumulation + S column sums. grid = BH * (N/256) = 768 blocks, 256 thr.
// LDS 49152 B (6x [64][64] bf16, XOR-swizzled chunks) -> 3 blocks/CU.
// ---------------------------------------------------------------------------
__global__ __launch_bounds__(256, 3) void proj_kernel(
    const float* __restrict__ x,
    const unsigned short* __restrict__ Whi, const unsigned short* __restrict__ Wlo,
    const float* __restrict__ bq, const float* __restrict__ bk,
    const float* __restrict__ bv,
    unsigned short* __restrict__ qout,
    float* __restrict__ kvraw, float* __restrict__ Sg)
{
    __shared__ __align__(16) char smem[49152];
    unsigned short* W_s = (unsigned short*)smem;   // 6 parts x [64][64], swizzled
    float* kvred = (float*)smem;                   // overlay: [4][32][66] fp32
    float* sred  = (float*)(smem + 33792);         // overlay: [4][64] fp32

    const int blk = blockIdx.x;
    const int nb  = blk & 31;            // N/256 = 32 chunks
    const int bh  = blk >> 5;
    const int b   = bh / H;
    const int h   = bh % H;
    const int n0  = nb * 256;
    const int t   = threadIdx.x;
    const int lane = t & 63;
    const int w   = t >> 6;
    const int lq  = lane & 15;
    const int qd  = lane >> 4;

    // ---- stage 6 weight parts, XOR-swizzle chunk index within each row ----
    {
        const size_t hb64 = (size_t)h * 64 * 64;
        for (int id = t; id < 512; id += 256) {
            int e = id >> 3, c = id & 7;
            int dc = ((c ^ (e & 7)) * 8);
            #pragma unroll
            for (int m = 0; m < 3; ++m) {
                const size_t src = ((size_t)m * H) * 64 * 64 + hb64 + e * 64 + c * 8;
                *(uint4*)&W_s[(2 * m) * 4096 + e * 64 + dc] = *(const uint4*)(Whi + src);
                *(uint4*)&W_s[(2 * m + 1) * 4096 + e * 64 + dc] = *(const uint4*)(Wlo + src);
            }
        }
    }

    float bqv[4], bkv[4], bvv[4];
    #pragma unroll
    for (int j = 0; j < 4; ++j) {
        int col = j * 16 + lq;
        bqv[j] = bq[h * D + col];
        bkv[j] = bk[h * D + col];
        bvv[j] = bv[h * D + col];
    }

    // A-fragment source: row w*16+lq of each 64-row sub-tile, cols qd*8 (+32)
    const float* xp = x + (size_t)(b * N + n0 + w * 16 + lq) * C + h * D + qd * 8;
    const size_t xstep = (size_t)64 * C;

    float4 cur0 = *(const float4*)xp;
    float4 cur1 = *(const float4*)(xp + 4);
    float4 cur2 = *(const float4*)(xp + 32);
    float4 cur3 = *(const float4*)(xp + 36);

    __syncthreads();   // W_s ready

    f32x4 kvacc[4][4] = {};
    float sacc[4] = {};

    for (int sub = 0; sub < 4; ++sub) {
        const int ns = n0 + sub * 64;
        // prefetch next sub's fragment (independent of current compute)
        float4 nx0, nx1, nx2, nx3;
        if (sub < 3) {
            const float* np = xp + (sub + 1) * xstep;
            nx0 = *(const float4*)np;
            nx1 = *(const float4*)(np + 4);
            nx2 = *(const float4*)(np + 32);
            nx3 = *(const float4*)(np + 36);
        }

        // ---- build hi/lo A-frags for both k-chunks ----
        float av[16];
        *(float4*)&av[0]  = cur0; *(float4*)&av[4]  = cur1;
        *(float4*)&av[8]  = cur2; *(float4*)&av[12] = cur3;
        short8 ahi[2], alo[2];
        #pragma unroll
        for (int ck = 0; ck < 2; ++ck)
            #pragma unroll
            for (int i = 0; i < 8; ++i) {
                float v = av[ck * 8 + i];
                unsigned short hb = f2bf(v);
                ahi[ck][i] = (short)hb;
                alo[ck][i] = (short)f2bf(v - bf2f(hb));
            }

        // ---- q/k/v MFMA (split-bf16, fp32-grade) ----
        f32x4 acc[3][4] = {};
        #pragma unroll
        for (int ck = 0; ck < 2; ++ck) {
            #pragma unroll
            for (int m = 0; m < 3; ++m) {
                #pragma unroll
                for (int j = 0; j < 4; ++j) {
                    const int row = j * 16 + lq;
                    const int pc = ((ck * 4 + qd) ^ (lq & 7)) * 8;   // swizzled chunk
                    short8 bhi = *(const short8*)&W_s[(2 * m) * 4096 + row * 64 + pc];
                    short8 blo = *(const short8*)&W_s[(2 * m + 1) * 4096 + row * 64 + pc];
                    acc[m][j] = __builtin_amdgcn_mfma_f32_16x16x32_bf16(alo[ck], bhi, acc[m][j], 0, 0, 0);
                    acc[m][j] = __builtin_amdgcn_mfma_f32_16x16x32_bf16(ahi[ck], blo, acc[m][j], 0, 0, 0);
                    acc[m][j] = __builtin_amdgcn_mfma_f32_16x16x32_bf16(ahi[ck], bhi, acc[m][j], 0, 0, 0);
                }
            }
        }

        // ---- q: bias + softmax over 64 cols -> direct scattered stores ----
        #pragma unroll
        for (int r = 0; r < 4; ++r) {
            float qv[4];
            #pragma unroll
            for (int j = 0; j < 4; ++j) qv[j] = acc[0][j][r] + bqv[j];
            float mx = fmaxf(fmaxf(qv[0], qv[1]), fmaxf(qv[2], qv[3]));
            #pragma unroll
            for (int msk = 1; msk < 16; msk <<= 1) mx = fmaxf(mx, __shfl_xor(mx, msk));
            float e0 = __expf(qv[0] - mx), e1 = __expf(qv[1] - mx);
            float e2 = __expf(qv[2] - mx), e3 = __expf(qv[3] - mx);
            float s = e0 + e1 + e2 + e3;
            #pragma unroll
            for (int msk = 1; msk < 16; msk <<= 1) s += __shfl_xor(s, msk);
            float inv = 1.f / s;
            unsigned short* qr =
                qout + ((size_t)bh * N + ns + w * 16 + qd * 4 + r) * 64 + lq;
            qr[0]  = f2bf(e0 * inv);
            qr[16] = f2bf(e1 * inv);
            qr[32] = f2bf(e2 * inv);
            qr[48] = f2bf(e3 * inv);
        }

        // ---- k' = exp(k) (no max needed, |k|<~6); v = (.+bv)*0.125 ----
        short8 kfrag[4], vfrag[4];
        #pragma unroll
        for (int j = 0; j < 4; ++j) {
            float e0 = __expf(acc[1][j][0] + bkv[j]);
            float e1 = __expf(acc[1][j][1] + bkv[j]);
            float e2 = __expf(acc[1][j][2] + bkv[j]);
            float e3 = __expf(acc[1][j][3] + bkv[j]);
            float cs = e0 + e1 + e2 + e3;
            cs += __shfl_xor(cs, 16);
            cs += __shfl_xor(cs, 32);
            sacc[j] += cs;
            kfrag[j] = short8{(short)f2bf(e0), (short)f2bf(e1),
                              (short)f2bf(e2), (short)f2bf(e3), 0, 0, 0, 0};
            float v0 = (acc[2][j][0] + bvv[j]) * 0.125f;
            float v1 = (acc[2][j][1] + bvv[j]) * 0.125f;
            float v2 = (acc[2][j][2] + bvv[j]) * 0.125f;
            float v3 = (acc[2][j][3] + bvv[j]) * 0.125f;
            vfrag[j] = short8{(short)f2bf(v0), (short)f2bf(v1),
                              (short)f2bf(v2), (short)f2bf(v3), 0, 0, 0, 0};
        }
        #pragma unroll
        for (int i = 0; i < 4; ++i)
            #pragma unroll
            for (int j = 0; j < 4; ++j)
                kvacc[i][j] = __builtin_amdgcn_mfma_f32_16x16x32_bf16(
                    kfrag[i], vfrag[j], kvacc[i][j], 0, 0, 0);

        cur0 = nx0; cur1 = nx1; cur2 = nx2; cur3 = nx3;
    }

    __syncthreads();   // all W_s reads done -> overlay region free

    // ---- cross-wave reduce in 2 halves (32 d-rows each), then atomics ----
    #pragma unroll
    for (int half = 0; half < 2; ++half) {
        #pragma unroll
        for (int i2 = 0; i2 < 2; ++i2) {
            const int ii = half * 2 + i2;
            #pragma unroll
            for (int j = 0; j < 4; ++j)
                #pragma unroll
                for (int r = 0; r < 4; ++r)
                    kvred[w * 2112 + (i2 * 16 + qd * 4 + r) * 66 + j * 16 + lq] =
                        kvacc[ii][j][r];
        }
        if (half == 0 && qd == 0) {
            #pragma unroll
            for (int j = 0; j < 4; ++j) sred[w * 64 + j * 16 + lq] = sacc[j];
        }
        __syncthreads();
        for (int idx = t; idx < 2048; idx += 256) {
            int dl = idx >> 6, e = idx & 63;
            float s = kvred[dl * 66 + e] + kvred[2112 + dl * 66 + e]
                    + kvred[2 * 2112 + dl * 66 + e] + kvred[3 * 2112 + dl * 66 + e];
            atomicAdd(&kvraw[bh * 4096 + (half * 32 + dl) * 64 + e], s);
        }
        if (half == 1 && t < 64) {
            float s = sred[t] + sred[64 + t] + sred[128 + t] + sred[192 + t];
            atomicAdd(&Sg[bh * 64 + t], s);
        }
        if (half == 0) __syncthreads();
    }
}

// ---------------------------------------------------------------------------
// Kernel 2: KWT[b][c][h*64+d] = sum_e (kvraw[bh][d][e]/S[d]) * Wp[c][h*64+e]
// ---------------------------------------------------------------------------
__global__ __launch_bounds__(256) void kw_kernel(
    const float* __restrict__ kvraw, const float* __restrict__ Sg,
    const float* __restrict__ Wp, unsigned short* __restrict__ KWT)
{
    __shared__ float kv_s[64 * 68];   // [e][d]
    __shared__ float w_s[64 * 68];    // [e][c]
    __shared__ float rS_s[64];
    const int bh = blockIdx.x / (C / 64);
    const int ct = blockIdx.x % (C / 64);
    const int b = bh / H, h = bh % H;
    const int c0 = ct * 64;
    const int t = threadIdx.x, dg = t >> 4, cg = t & 15;

    if (t < 64) rS_s[t] = 1.f / Sg[bh * 64 + t];
    __syncthreads();

    for (int i = t; i < 4096; i += 256) {
        int row = i >> 6, e = i & 63;
        kv_s[e * 68 + row] = kvraw[bh * (D * D) + row * 64 + e] * rS_s[row];
        w_s[e * 68 + row]  = Wp[(size_t)(c0 + row) * C + h * 64 + e];
    }
    __syncthreads();

    float acc[4][4] = {};
    for (int e = 0; e < 64; ++e) {
        float4 a = *(float4*)&kv_s[e * 68 + dg * 4];
        float4 w = *(float4*)&w_s[e * 68 + cg * 4];
        const float a4[4] = {a.x, a.y, a.z, a.w};
        const float w4[4] = {w.x, w.y, w.z, w.w};
        #pragma unroll
        for (int i = 0; i < 4; ++i)
            #pragma unroll
            for (int j = 0; j < 4; ++j) acc[i][j] += a4[i] * w4[j];
    }
    #pragma unroll
    for (int i = 0; i < 4; ++i)
        #pragma unroll
        for (int j = 0; j < 4; ++j) {
            int d = dg * 4 + i, c = c0 + cg * 4 + j;
            KWT[((size_t)b * C + c) * (H * D) + h * 64 + d] = f2bf(acc[i][j]);
        }
}

// ---------------------------------------------------------------------------
// Kernel 3 (MFMA): out[m][c] = sum_k q[m][k] * KWT[c][k] + bp[c]
// ---------------------------------------------------------------------------
__global__ __launch_bounds__(256) void out_gemm(
    const unsigned short* __restrict__ q, const unsigned short* __restrict__ KWT,
    const float* __restrict__ bp, float* __restrict__ out)
{
    __shared__ __align__(16) unsigned short A_s[128 * 72];
    __shared__ __align__(16) unsigned short B_s[128 * 72];

    const int mt = blockIdx.x / (C / 128);
    const int ct = blockIdx.x % (C / 128);
    const int m0 = mt * 128, c0 = ct * 128;
    const int b  = m0 >> 13;
    const int n0 = m0 & (N - 1);
    const int t  = threadIdx.x;
    const int lane = t & 63;
    const int w  = t >> 6;
    const int wm = w >> 1, wn = w & 1;
    const int lq = lane & 15;
    const int qd = lane >> 4;

    f32x4 acc[4][4] = {};

    for (int h = 0; h < H; ++h) {
        if (h) __syncthreads();
        const unsigned short* qb = q + (size_t)(b * H + h) * N * D + (size_t)n0 * D;
        const unsigned short* kb = KWT + ((size_t)b * C + c0) * (H * D) + h * 64;
        #pragma unroll
        for (int it = 0; it < 4; ++it) {
            int id = it * 256 + t;
            int r = id >> 3, c8 = id & 7;
            *(uint4*)&A_s[r * 72 + c8 * 8] = *(const uint4*)(qb + r * 64 + c8 * 8);
            *(uint4*)&B_s[r * 72 + c8 * 8] = *(const uint4*)(kb + (size_t)r * (H * D) + c8 * 8);
        }
        __syncthreads();

        #pragma unroll
        for (int kk = 0; kk < 64; kk += 32) {
            short8 af[4], bf[4];
            #pragma unroll
            for (int i = 0; i < 4; ++i)
                af[i] = *(short8*)&A_s[(wm * 64 + i * 16 + lq) * 72 + kk + qd * 8];
            #pragma unroll
            for (int j = 0; j < 4; ++j)
                bf[j] = *(short8*)&B_s[(wn * 64 + j * 16 + lq) * 72 + kk + qd * 8];
            #pragma unroll
            for (int i = 0; i < 4; ++i)
                #pragma unroll
                for (int j = 0; j < 4; ++j)
                    acc[i][j] = __builtin_amdgcn_mfma_f32_16x16x32_bf16(
                        af[i], bf[j], acc[i][j], 0, 0, 0);
        }
    }

    float bpv[4];
    #pragma unroll
    for (int j = 0; j < 4; ++j) bpv[j] = bp[c0 + wn * 64 + j * 16 + lq];

    #pragma unroll
    for (int i = 0; i < 4; ++i) {
        #pragma unroll
        for (int r = 0; r < 4; ++r) {
            size_t row = (size_t)m0 + wm * 64 + i * 16 + qd * 4 + r;
            float* orow = out + row * C + c0 + wn * 64;
            #pragma unroll
            for (int j = 0; j < 4; ++j)
                orow[j * 16 + lq] = acc[i][j][r] + bpv[j];
        }
    }
}

// ---------------------------------------------------------------------------
extern "C" void kernel_launch(void* const* d_in, const int* in_sizes, int n_in,
                              void* d_out, int out_size, void* d_ws, size_t ws_size,
                              hipStream_t stream)
{
    const float* x  = (const float*)d_in[0];
    const float* Wq = (const float*)d_in[1];
    const float* bq = (const float*)d_in[2];
    const float* Wk = (const float*)d_in[3];
    const float* bk = (const float*)d_in[4];
    const float* Wv = (const float*)d_in[5];
    const float* bv = (const float*)d_in[6];
    const float* Wp = (const float*)d_in[7];
    const float* bp = (const float*)d_in[8];
    float* out = (float*)d_out;

    const size_t SZ = (size_t)B * H * N * D;
    float* ws   = (float*)d_ws;
    unsigned short* q = (unsigned short*)ws;          // [BH, N, D] bf16
    float* kvraw = ws + SZ;                           // [BH, 64, 64] fp32
    float* Sg    = kvraw + (size_t)BH * D * D;        // [BH, 64] fp32
    unsigned short* KWT = (unsigned short*)(Sg + BH * 64);     // [B, C, H*D] bf16
    unsigned short* Whi = KWT + (size_t)B * C * (H * D);       // [3,H,64,64] bf16
    unsigned short* Wlo = Whi + (size_t)3 * H * 64 * 64;

    wprep<<<3 * H, 64, 0, stream>>>(Wq, Wk, Wv, Whi, Wlo);
    hipMemsetAsync(kvraw, 0, ((size_t)BH * D * D + BH * 64) * sizeof(float), stream);
    proj_kernel<<<BH * (N / 256), 256, 0, stream>>>(x, Whi, Wlo, bq, bk, bv,
                                                    q, kvraw, Sg);
    kw_kernel<<<BH * (C / 64), 256, 0, stream>>>(kvraw, Sg, Wp, KWT);
    out_gemm<<<(BN / 128) * (C / 128), 256, 0, stream>>>(q, KWT, bp, out);
}

// Round 8
// 239.621 us; speedup vs baseline: 1.4160x; 1.4160x over previous
//
#include <hip/hip_runtime.h>
#include <hip/hip_bf16.h>

// EfficientAttention: B=4, N=8192, C=384, H=6, D=64
// Round 8: round-7 structure with register discipline (r7 spilled: VGPR=84 vs
// ~140 live -> 530 MB scratch traffic). launch_bounds(256,2), no prefetch,
// per-matrix sequential MFMA with early acc retirement.

#define B 4
#define N 8192
#define C 384
#define H 6
#define D 64
#define BH (B * H)   // 24
#define BN (B * N)   // 32768

typedef __attribute__((ext_vector_type(8))) short short8;
typedef __attribute__((ext_vector_type(4))) float f32x4;

__device__ inline unsigned short f2bf(float f) {
    unsigned int u = __float_as_uint(f);
    unsigned int r = (u + 0x7fff + ((u >> 16) & 1)) >> 16;   // RNE
    return (unsigned short)r;
}
__device__ inline float bf2f(unsigned short h) {
    return __uint_as_float(((unsigned int)h) << 16);
}

// ---------------------------------------------------------------------------
// Kernel 0: transpose + hi/lo-split the three weight sets.
// Whi/Wlo layout: [mat][h][e][d] bf16, value = W[d][e]  (B-operand rows = e).
// ---------------------------------------------------------------------------
__global__ void wprep(const float* __restrict__ Wq, const float* __restrict__ Wk,
                      const float* __restrict__ Wv,
                      unsigned short* __restrict__ Whi, unsigned short* __restrict__ Wlo)
{
    __shared__ float tmp[64][65];
    const int m = blockIdx.x / H;
    const int h = blockIdx.x % H;
    const float* in = (m == 0 ? Wq : m == 1 ? Wk : Wv) + h * 64 * 64;
    const int t = threadIdx.x;
    for (int d = 0; d < 64; ++d) tmp[d][t] = in[d * 64 + t];   // tmp[d][e]
    __syncthreads();
    const size_t base = ((size_t)(m * H + h)) * 64 * 64;
    for (int e = 0; e < 64; ++e) {
        float v = tmp[t][e];                    // W[d=t][e] -> out[e][d=t]
        unsigned short hb = f2bf(v);
        Whi[base + e * 64 + t] = hb;
        Wlo[base + e * 64 + t] = f2bf(v - bf2f(hb));
    }
}

// ---------------------------------------------------------------------------
// Kernel 1 (MFMA): per-head QKV projection + q softmax + fused kv-partial
// accumulation + S column sums. grid = BH * (N/256) = 768 blocks, 256 thr.
// LDS 49152 B (6x [64][64] bf16, XOR-swizzled chunks).
// ---------------------------------------------------------------------------
__global__ __launch_bounds__(256, 2) void proj_kernel(
    const float* __restrict__ x,
    const unsigned short* __restrict__ Whi, const unsigned short* __restrict__ Wlo,
    const float* __restrict__ bq, const float* __restrict__ bk,
    const float* __restrict__ bv,
    unsigned short* __restrict__ qout,
    float* __restrict__ kvraw, float* __restrict__ Sg)
{
    __shared__ __align__(16) char smem[49152];
    unsigned short* W_s = (unsigned short*)smem;   // 6 parts x [64][64], swizzled
    float* kvred = (float*)smem;                   // overlay: [4][32][66] fp32
    float* sred  = (float*)(smem + 33792);         // overlay: [4][64] fp32

    const int blk = blockIdx.x;
    const int nb  = blk & 31;            // N/256 = 32 chunks
    const int bh  = blk >> 5;
    const int b   = bh / H;
    const int h   = bh % H;
    const int n0  = nb * 256;
    const int t   = threadIdx.x;
    const int lane = t & 63;
    const int w   = t >> 6;
    const int lq  = lane & 15;
    const int qd  = lane >> 4;

    // ---- stage 6 weight parts, XOR-swizzle chunk index within each row ----
    {
        const size_t hb64 = (size_t)h * 64 * 64;
        for (int id = t; id < 512; id += 256) {
            int e = id >> 3, c = id & 7;
            int dc = ((c ^ (e & 7)) * 8);
            #pragma unroll
            for (int m = 0; m < 3; ++m) {
                const size_t src = ((size_t)m * H) * 64 * 64 + hb64 + e * 64 + c * 8;
                *(uint4*)&W_s[(2 * m) * 4096 + e * 64 + dc] = *(const uint4*)(Whi + src);
                *(uint4*)&W_s[(2 * m + 1) * 4096 + e * 64 + dc] = *(const uint4*)(Wlo + src);
            }
        }
    }

    float bqv[4], bkv[4], bvv[4];
    #pragma unroll
    for (int j = 0; j < 4; ++j) {
        int col = j * 16 + lq;
        bqv[j] = bq[h * D + col];
        bkv[j] = bk[h * D + col];
        bvv[j] = bv[h * D + col];
    }

    __syncthreads();   // W_s ready

    f32x4 kvacc[4][4] = {};
    float sacc[4] = {};

    for (int sub = 0; sub < 4; ++sub) {
        const int ns = n0 + sub * 64;

        // ---- A-fragment: row w*16+lq, cols qd*8.. and 32+qd*8.. ----
        const float* ap = x + (size_t)(b * N + ns + w * 16 + lq) * C + h * D + qd * 8;
        short8 ahi[2], alo[2];
        {
            float av[16];
            *(float4*)&av[0]  = *(const float4*)ap;
            *(float4*)&av[4]  = *(const float4*)(ap + 4);
            *(float4*)&av[8]  = *(const float4*)(ap + 32);
            *(float4*)&av[12] = *(const float4*)(ap + 36);
            #pragma unroll
            for (int ck = 0; ck < 2; ++ck)
                #pragma unroll
                for (int i = 0; i < 8; ++i) {
                    float v = av[ck * 8 + i];
                    unsigned short hb = f2bf(v);
                    ahi[ck][i] = (short)hb;
                    alo[ck][i] = (short)f2bf(v - bf2f(hb));
                }
        }

        // ---- m = 0 (q): MFMA, then retire to softmax + stores ----
        {
            f32x4 acc[4] = {};
            #pragma unroll
            for (int ck = 0; ck < 2; ++ck)
                #pragma unroll
                for (int j = 0; j < 4; ++j) {
                    const int row = j * 16 + lq;
                    const int pc = ((ck * 4 + qd) ^ (lq & 7)) * 8;
                    short8 bhi = *(const short8*)&W_s[row * 64 + pc];
                    short8 blo = *(const short8*)&W_s[4096 + row * 64 + pc];
                    acc[j] = __builtin_amdgcn_mfma_f32_16x16x32_bf16(alo[ck], bhi, acc[j], 0, 0, 0);
                    acc[j] = __builtin_amdgcn_mfma_f32_16x16x32_bf16(ahi[ck], blo, acc[j], 0, 0, 0);
                    acc[j] = __builtin_amdgcn_mfma_f32_16x16x32_bf16(ahi[ck], bhi, acc[j], 0, 0, 0);
                }
            #pragma unroll
            for (int r = 0; r < 4; ++r) {
                float qv[4];
                #pragma unroll
                for (int j = 0; j < 4; ++j) qv[j] = acc[j][r] + bqv[j];
                float mx = fmaxf(fmaxf(qv[0], qv[1]), fmaxf(qv[2], qv[3]));
                #pragma unroll
                for (int msk = 1; msk < 16; msk <<= 1) mx = fmaxf(mx, __shfl_xor(mx, msk));
                float e0 = __expf(qv[0] - mx), e1 = __expf(qv[1] - mx);
                float e2 = __expf(qv[2] - mx), e3 = __expf(qv[3] - mx);
                float s = e0 + e1 + e2 + e3;
                #pragma unroll
                for (int msk = 1; msk < 16; msk <<= 1) s += __shfl_xor(s, msk);
                float inv = 1.f / s;
                unsigned short* qr =
                    qout + ((size_t)bh * N + ns + w * 16 + qd * 4 + r) * 64 + lq;
                qr[0]  = f2bf(e0 * inv);
                qr[16] = f2bf(e1 * inv);
                qr[32] = f2bf(e2 * inv);
                qr[48] = f2bf(e3 * inv);
            }
        }

        // ---- m = 1 (k): MFMA, retire to exp -> kfrag + S partial ----
        short8 kfrag[4];
        {
            f32x4 acc[4] = {};
            #pragma unroll
            for (int ck = 0; ck < 2; ++ck)
                #pragma unroll
                for (int j = 0; j < 4; ++j) {
                    const int row = j * 16 + lq;
                    const int pc = ((ck * 4 + qd) ^ (lq & 7)) * 8;
                    short8 bhi = *(const short8*)&W_s[2 * 4096 + row * 64 + pc];
                    short8 blo = *(const short8*)&W_s[3 * 4096 + row * 64 + pc];
                    acc[j] = __builtin_amdgcn_mfma_f32_16x16x32_bf16(alo[ck], bhi, acc[j], 0, 0, 0);
                    acc[j] = __builtin_amdgcn_mfma_f32_16x16x32_bf16(ahi[ck], blo, acc[j], 0, 0, 0);
                    acc[j] = __builtin_amdgcn_mfma_f32_16x16x32_bf16(ahi[ck], bhi, acc[j], 0, 0, 0);
                }
            #pragma unroll
            for (int j = 0; j < 4; ++j) {
                float e0 = __expf(acc[j][0] + bkv[j]);
                float e1 = __expf(acc[j][1] + bkv[j]);
                float e2 = __expf(acc[j][2] + bkv[j]);
                float e3 = __expf(acc[j][3] + bkv[j]);
                float cs = e0 + e1 + e2 + e3;
                cs += __shfl_xor(cs, 16);
                cs += __shfl_xor(cs, 32);
                sacc[j] += cs;
                kfrag[j] = short8{(short)f2bf(e0), (short)f2bf(e1),
                                  (short)f2bf(e2), (short)f2bf(e3), 0, 0, 0, 0};
            }
        }

        // ---- m = 2 (v): MFMA, retire to vfrag, then kv accumulate ----
        {
            f32x4 acc[4] = {};
            #pragma unroll
            for (int ck = 0; ck < 2; ++ck)
                #pragma unroll
                for (int j = 0; j < 4; ++j) {
                    const int row = j * 16 + lq;
                    const int pc = ((ck * 4 + qd) ^ (lq & 7)) * 8;
                    short8 bhi = *(const short8*)&W_s[4 * 4096 + row * 64 + pc];
                    short8 blo = *(const short8*)&W_s[5 * 4096 + row * 64 + pc];
                    acc[j] = __builtin_amdgcn_mfma_f32_16x16x32_bf16(alo[ck], bhi, acc[j], 0, 0, 0);
                    acc[j] = __builtin_amdgcn_mfma_f32_16x16x32_bf16(ahi[ck], blo, acc[j], 0, 0, 0);
                    acc[j] = __builtin_amdgcn_mfma_f32_16x16x32_bf16(ahi[ck], bhi, acc[j], 0, 0, 0);
                }
            short8 vfrag[4];
            #pragma unroll
            for (int j = 0; j < 4; ++j) {
                float v0 = (acc[j][0] + bvv[j]) * 0.125f;
                float v1 = (acc[j][1] + bvv[j]) * 0.125f;
                float v2 = (acc[j][2] + bvv[j]) * 0.125f;
                float v3 = (acc[j][3] + bvv[j]) * 0.125f;
                vfrag[j] = short8{(short)f2bf(v0), (short)f2bf(v1),
                                  (short)f2bf(v2), (short)f2bf(v3), 0, 0, 0, 0};
            }
            #pragma unroll
            for (int i = 0; i < 4; ++i)
                #pragma unroll
                for (int j = 0; j < 4; ++j)
                    kvacc[i][j] = __builtin_amdgcn_mfma_f32_16x16x32_bf16(
                        kfrag[i], vfrag[j], kvacc[i][j], 0, 0, 0);
        }
    }

    __syncthreads();   // all W_s reads done -> overlay region free

    // ---- cross-wave reduce in 2 halves (32 d-rows each), then atomics ----
    #pragma unroll
    for (int half = 0; half < 2; ++half) {
        #pragma unroll
        for (int i2 = 0; i2 < 2; ++i2) {
            const int ii = half * 2 + i2;
            #pragma unroll
            for (int j = 0; j < 4; ++j)
                #pragma unroll
                for (int r = 0; r < 4; ++r)
                    kvred[w * 2112 + (i2 * 16 + qd * 4 + r) * 66 + j * 16 + lq] =
                        kvacc[ii][j][r];
        }
        if (half == 0 && qd == 0) {
            #pragma unroll
            for (int j = 0; j < 4; ++j) sred[w * 64 + j * 16 + lq] = sacc[j];
        }
        __syncthreads();
        for (int idx = t; idx < 2048; idx += 256) {
            int dl = idx >> 6, e = idx & 63;
            float s = kvred[dl * 66 + e] + kvred[2112 + dl * 66 + e]
                    + kvred[2 * 2112 + dl * 66 + e] + kvred[3 * 2112 + dl * 66 + e];
            atomicAdd(&kvraw[bh * 4096 + (half * 32 + dl) * 64 + e], s);
        }
        if (half == 1 && t < 64) {
            float s = sred[t] + sred[64 + t] + sred[128 + t] + sred[192 + t];
            atomicAdd(&Sg[bh * 64 + t], s);
        }
        if (half == 0) __syncthreads();
    }
}

// ---------------------------------------------------------------------------
// Kernel 2: KWT[b][c][h*64+d] = sum_e (kvraw[bh][d][e]/S[d]) * Wp[c][h*64+e]
// ---------------------------------------------------------------------------
__global__ __launch_bounds__(256) void kw_kernel(
    const float* __restrict__ kvraw, const float* __restrict__ Sg,
    const float* __restrict__ Wp, unsigned short* __restrict__ KWT)
{
    __shared__ float kv_s[64 * 68];   // [e][d]
    __shared__ float w_s[64 * 68];    // [e][c]
    __shared__ float rS_s[64];
    const int bh = blockIdx.x / (C / 64);
    const int ct = blockIdx.x % (C / 64);
    const int b = bh / H, h = bh % H;
    const int c0 = ct * 64;
    const int t = threadIdx.x, dg = t >> 4, cg = t & 15;

    if (t < 64) rS_s[t] = 1.f / Sg[bh * 64 + t];
    __syncthreads();

    for (int i = t; i < 4096; i += 256) {
        int row = i >> 6, e = i & 63;
        kv_s[e * 68 + row] = kvraw[bh * (D * D) + row * 64 + e] * rS_s[row];
        w_s[e * 68 + row]  = Wp[(size_t)(c0 + row) * C + h * 64 + e];
    }
    __syncthreads();

    float acc[4][4] = {};
    for (int e = 0; e < 64; ++e) {
        float4 a = *(float4*)&kv_s[e * 68 + dg * 4];
        float4 w = *(float4*)&w_s[e * 68 + cg * 4];
        const float a4[4] = {a.x, a.y, a.z, a.w};
        const float w4[4] = {w.x, w.y, w.z, w.w};
        #pragma unroll
        for (int i = 0; i < 4; ++i)
            #pragma unroll
            for (int j = 0; j < 4; ++j) acc[i][j] += a4[i] * w4[j];
    }
    #pragma unroll
    for (int i = 0; i < 4; ++i)
        #pragma unroll
        for (int j = 0; j < 4; ++j) {
            int d = dg * 4 + i, c = c0 + cg * 4 + j;
            KWT[((size_t)b * C + c) * (H * D) + h * 64 + d] = f2bf(acc[i][j]);
        }
}

// ---------------------------------------------------------------------------
// Kernel 3 (MFMA): out[m][c] = sum_k q[m][k] * KWT[c][k] + bp[c]
// ---------------------------------------------------------------------------
__global__ __launch_bounds__(256) void out_gemm(
    const unsigned short* __restrict__ q, const unsigned short* __restrict__ KWT,
    const float* __restrict__ bp, float* __restrict__ out)
{
    __shared__ __align__(16) unsigned short A_s[128 * 72];
    __shared__ __align__(16) unsigned short B_s[128 * 72];

    const int mt = blockIdx.x / (C / 128);
    const int ct = blockIdx.x % (C / 128);
    const int m0 = mt * 128, c0 = ct * 128;
    const int b  = m0 >> 13;
    const int n0 = m0 & (N - 1);
    const int t  = threadIdx.x;
    const int lane = t & 63;
    const int w  = t >> 6;
    const int wm = w >> 1, wn = w & 1;
    const int lq = lane & 15;
    const int qd = lane >> 4;

    f32x4 acc[4][4] = {};

    for (int h = 0; h < H; ++h) {
        if (h) __syncthreads();
        const unsigned short* qb = q + (size_t)(b * H + h) * N * D + (size_t)n0 * D;
        const unsigned short* kb = KWT + ((size_t)b * C + c0) * (H * D) + h * 64;
        #pragma unroll
        for (int it = 0; it < 4; ++it) {
            int id = it * 256 + t;
            int r = id >> 3, c8 = id & 7;
            *(uint4*)&A_s[r * 72 + c8 * 8] = *(const uint4*)(qb + r * 64 + c8 * 8);
            *(uint4*)&B_s[r * 72 + c8 * 8] = *(const uint4*)(kb + (size_t)r * (H * D) + c8 * 8);
        }
        __syncthreads();

        #pragma unroll
        for (int kk = 0; kk < 64; kk += 32) {
            short8 af[4], bf[4];
            #pragma unroll
            for (int i = 0; i < 4; ++i)
                af[i] = *(short8*)&A_s[(wm * 64 + i * 16 + lq) * 72 + kk + qd * 8];
            #pragma unroll
            for (int j = 0; j < 4; ++j)
                bf[j] = *(short8*)&B_s[(wn * 64 + j * 16 + lq) * 72 + kk + qd * 8];
            #pragma unroll
            for (int i = 0; i < 4; ++i)
                #pragma unroll
                for (int j = 0; j < 4; ++j)
                    acc[i][j] = __builtin_amdgcn_mfma_f32_16x16x32_bf16(
                        af[i], bf[j], acc[i][j], 0, 0, 0);
        }
    }

    float bpv[4];
    #pragma unroll
    for (int j = 0; j < 4; ++j) bpv[j] = bp[c0 + wn * 64 + j * 16 + lq];

    #pragma unroll
    for (int i = 0; i < 4; ++i) {
        #pragma unroll
        for (int r = 0; r < 4; ++r) {
            size_t row = (size_t)m0 + wm * 64 + i * 16 + qd * 4 + r;
            float* orow = out + row * C + c0 + wn * 64;
            #pragma unroll
            for (int j = 0; j < 4; ++j)
                orow[j * 16 + lq] = acc[i][j][r] + bpv[j];
        }
    }
}

// ---------------------------------------------------------------------------
extern "C" void kernel_launch(void* const* d_in, const int* in_sizes, int n_in,
                              void* d_out, int out_size, void* d_ws, size_t ws_size,
                              hipStream_t stream)
{
    const float* x  = (const float*)d_in[0];
    const float* Wq = (const float*)d_in[1];
    const float* bq = (const float*)d_in[2];
    const float* Wk = (const float*)d_in[3];
    const float* bk = (const float*)d_in[4];
    const float* Wv = (const float*)d_in[5];
    const float* bv = (const float*)d_in[6];
    const float* Wp = (const float*)d_in[7];
    const float* bp = (const float*)d_in[8];
    float* out = (float*)d_out;

    const size_t SZ = (size_t)B * H * N * D;
    float* ws   = (float*)d_ws;
    unsigned short* q = (unsigned short*)ws;          // [BH, N, D] bf16
    float* kvraw = ws + SZ;                           // [BH, 64, 64] fp32
    float* Sg    = kvraw + (size_t)BH * D * D;        // [BH, 64] fp32
    unsigned short* KWT = (unsigned short*)(Sg + BH * 64);     // [B, C, H*D] bf16
    unsigned short* Whi = KWT + (size_t)B * C * (H * D);       // [3,H,64,64] bf16
    unsigned short* Wlo = Whi + (size_t)3 * H * 64 * 64;

    wprep<<<3 * H, 64, 0, stream>>>(Wq, Wk, Wv, Whi, Wlo);
    hipMemsetAsync(kvraw, 0, ((size_t)BH * D * D + BH * 64) * sizeof(float), stream);
    proj_kernel<<<BH * (N / 256), 256, 0, stream>>>(x, Whi, Wlo, bq, bk, bv,
                                                    q, kvraw, Sg);
    kw_kernel<<<BH * (C / 64), 256, 0, stream>>>(kvraw, Sg, Wp, KWT);
    out_gemm<<<(BN / 128) * (C / 128), 256, 0, stream>>>(q, KWT, bp, out);
}

// Round 9
// 156.058 us; speedup vs baseline: 2.1742x; 1.5355x over previous
//
#include <hip/hip_runtime.h>
#include <hip/hip_bf16.h>

// EfficientAttention: B=4, N=8192, C=384, H=6, D=64
// Round 9: proj precision right-sized to bf16 (consumers are bf16 anyway):
// single MFMA per product (was 3x split-bf16), W_s 24.6 KB, per-wave qbuf
// (no barriers in loop), sched_barrier fences to stop pipelining spills.

#define B 4
#define N 8192
#define C 384
#define H 6
#define D 64
#define BH (B * H)   // 24
#define BN (B * N)   // 32768

typedef __attribute__((ext_vector_type(8))) short short8;
typedef __attribute__((ext_vector_type(4))) float f32x4;

__device__ inline unsigned short f2bf(float f) {
    unsigned int u = __float_as_uint(f);
    unsigned int r = (u + 0x7fff + ((u >> 16) & 1)) >> 16;   // RNE
    return (unsigned short)r;
}

// ---------------------------------------------------------------------------
// Kernel 0: transpose the three weight sets to bf16 B-operand layout.
// Wt layout: [mat][h][e][d] bf16, value = W[d][e].
// ---------------------------------------------------------------------------
__global__ void wprep(const float* __restrict__ Wq, const float* __restrict__ Wk,
                      const float* __restrict__ Wv, unsigned short* __restrict__ Wt)
{
    __shared__ float tmp[64][65];
    const int m = blockIdx.x / H;
    const int h = blockIdx.x % H;
    const float* in = (m == 0 ? Wq : m == 1 ? Wk : Wv) + h * 64 * 64;
    const int t = threadIdx.x;
    for (int d = 0; d < 64; ++d) tmp[d][t] = in[d * 64 + t];   // tmp[d][e]
    __syncthreads();
    const size_t base = ((size_t)(m * H + h)) * 64 * 64;
    for (int e = 0; e < 64; ++e)
        Wt[base + e * 64 + t] = f2bf(tmp[t][e]);   // out[e][d=t] = W[d=t][e]
}

// ---------------------------------------------------------------------------
// Kernel 1 (MFMA): per-head QKV projection (bf16) + q softmax + fused
// kv-partial accumulation + S column sums.
// grid = BH * (N/256) = 768 blocks, 256 threads. LDS 34816 B.
// ---------------------------------------------------------------------------
__global__ __launch_bounds__(256, 2) void proj_kernel(
    const float* __restrict__ x, const unsigned short* __restrict__ Wt,
    const float* __restrict__ bq, const float* __restrict__ bk,
    const float* __restrict__ bv,
    unsigned short* __restrict__ qout,
    float* __restrict__ kvraw, float* __restrict__ Sg)
{
    __shared__ __align__(16) char smem[34816];
    unsigned short* W_s = (unsigned short*)smem;       // 3 x [64][64], swizzled
    unsigned short* qbuf = (unsigned short*)(smem + 24576); // per-wave [16][72]
    float* kvred = (float*)smem;                       // overlay: [4][32][66]
    float* sred  = (float*)(smem + 33792);             // overlay: [4][64]

    const int blk = blockIdx.x;
    const int nb  = blk & 31;            // N/256 = 32 chunks
    const int bh  = blk >> 5;
    const int b   = bh / H;
    const int h   = bh % H;
    const int n0  = nb * 256;
    const int t   = threadIdx.x;
    const int lane = t & 63;
    const int w   = t >> 6;
    const int lq  = lane & 15;
    const int qd  = lane >> 4;

    // ---- stage 3 weight parts, XOR-swizzled chunks within each row ----
    {
        const size_t hb = (size_t)h * 4096;
        for (int id = t; id < 512; id += 256) {
            int e = id >> 3, c = id & 7;
            int dc = ((c ^ (e & 7)) * 8);
            #pragma unroll
            for (int m = 0; m < 3; ++m)
                *(uint4*)&W_s[m * 4096 + e * 64 + dc] =
                    *(const uint4*)(Wt + (size_t)m * H * 4096 + hb + e * 64 + c * 8);
        }
    }

    float bqv[4], bkv[4], bvv[4];
    #pragma unroll
    for (int j = 0; j < 4; ++j) {
        int col = j * 16 + lq;
        bqv[j] = bq[h * D + col];
        bkv[j] = bk[h * D + col];
        bvv[j] = bv[h * D + col];
    }

    unsigned short* qw = qbuf + w * 1152;   // this wave's [16][72] region

    __syncthreads();   // W_s ready

    f32x4 kvacc[4][4] = {};
    float sacc[4] = {};

    for (int sub = 0; sub < 4; ++sub) {
        const int ns = n0 + sub * 64;

        // ---- A-fragment direct from global: row w*16+lq, k-chunks qd*8 ----
        const float* ap = x + (size_t)(b * N + ns + w * 16 + lq) * C + h * D + qd * 8;
        short8 af[2];
        {
            float av[16];
            *(float4*)&av[0]  = *(const float4*)ap;
            *(float4*)&av[4]  = *(const float4*)(ap + 4);
            *(float4*)&av[8]  = *(const float4*)(ap + 32);
            *(float4*)&av[12] = *(const float4*)(ap + 36);
            #pragma unroll
            for (int ck = 0; ck < 2; ++ck)
                #pragma unroll
                for (int i = 0; i < 8; ++i)
                    af[ck][i] = (short)f2bf(av[ck * 8 + i]);
        }

        // ---- m = 0 (q): MFMA -> softmax -> qbuf (wave-local) -> global ----
        {
            f32x4 acc[4] = {};
            #pragma unroll
            for (int ck = 0; ck < 2; ++ck)
                #pragma unroll
                for (int j = 0; j < 4; ++j) {
                    const int pc = ((ck * 4 + qd) ^ (lq & 7)) * 8;
                    short8 bw = *(const short8*)&W_s[(j * 16 + lq) * 64 + pc];
                    acc[j] = __builtin_amdgcn_mfma_f32_16x16x32_bf16(af[ck], bw, acc[j], 0, 0, 0);
                }
            #pragma unroll
            for (int r = 0; r < 4; ++r) {
                float qv[4];
                #pragma unroll
                for (int j = 0; j < 4; ++j) qv[j] = acc[j][r] + bqv[j];
                float mx = fmaxf(fmaxf(qv[0], qv[1]), fmaxf(qv[2], qv[3]));
                #pragma unroll
                for (int msk = 1; msk < 16; msk <<= 1) mx = fmaxf(mx, __shfl_xor(mx, msk));
                float e0 = __expf(qv[0] - mx), e1 = __expf(qv[1] - mx);
                float e2 = __expf(qv[2] - mx), e3 = __expf(qv[3] - mx);
                float s = e0 + e1 + e2 + e3;
                #pragma unroll
                for (int msk = 1; msk < 16; msk <<= 1) s += __shfl_xor(s, msk);
                float inv = 1.f / s;
                const int row = qd * 4 + r;
                qw[row * 72 + 0 * 16 + lq] = f2bf(e0 * inv);
                qw[row * 72 + 1 * 16 + lq] = f2bf(e1 * inv);
                qw[row * 72 + 2 * 16 + lq] = f2bf(e2 * inv);
                qw[row * 72 + 3 * 16 + lq] = f2bf(e3 * inv);
            }
            // wave-local readback -> coalesced 16B global stores (no barrier)
            const size_t gbase = (size_t)bh * N + ns + w * 16;
            #pragma unroll
            for (int rep = 0; rep < 2; ++rep) {
                int flat = rep * 64 + lane;
                int row = flat >> 3, c8 = flat & 7;
                *(uint4*)&qout[(gbase + row) * 64 + c8 * 8] =
                    *(uint4*)&qw[row * 72 + c8 * 8];
            }
        }
        __builtin_amdgcn_sched_barrier(0);

        // ---- m = 1 (k): MFMA -> exp -> kfrag + S partial ----
        short8 kfrag[4];
        {
            f32x4 acc[4] = {};
            #pragma unroll
            for (int ck = 0; ck < 2; ++ck)
                #pragma unroll
                for (int j = 0; j < 4; ++j) {
                    const int pc = ((ck * 4 + qd) ^ (lq & 7)) * 8;
                    short8 bw = *(const short8*)&W_s[4096 + (j * 16 + lq) * 64 + pc];
                    acc[j] = __builtin_amdgcn_mfma_f32_16x16x32_bf16(af[ck], bw, acc[j], 0, 0, 0);
                }
            #pragma unroll
            for (int j = 0; j < 4; ++j) {
                float e0 = __expf(acc[j][0] + bkv[j]);
                float e1 = __expf(acc[j][1] + bkv[j]);
                float e2 = __expf(acc[j][2] + bkv[j]);
                float e3 = __expf(acc[j][3] + bkv[j]);
                float cs = e0 + e1 + e2 + e3;
                cs += __shfl_xor(cs, 16);
                cs += __shfl_xor(cs, 32);
                sacc[j] += cs;
                kfrag[j] = short8{(short)f2bf(e0), (short)f2bf(e1),
                                  (short)f2bf(e2), (short)f2bf(e3), 0, 0, 0, 0};
            }
        }
        __builtin_amdgcn_sched_barrier(0);

        // ---- m = 2 (v): MFMA -> vfrag -> kv accumulate ----
        {
            f32x4 acc[4] = {};
            #pragma unroll
            for (int ck = 0; ck < 2; ++ck)
                #pragma unroll
                for (int j = 0; j < 4; ++j) {
                    const int pc = ((ck * 4 + qd) ^ (lq & 7)) * 8;
                    short8 bw = *(const short8*)&W_s[2 * 4096 + (j * 16 + lq) * 64 + pc];
                    acc[j] = __builtin_amdgcn_mfma_f32_16x16x32_bf16(af[ck], bw, acc[j], 0, 0, 0);
                }
            short8 vfrag[4];
            #pragma unroll
            for (int j = 0; j < 4; ++j) {
                float v0 = (acc[j][0] + bvv[j]) * 0.125f;
                float v1 = (acc[j][1] + bvv[j]) * 0.125f;
                float v2 = (acc[j][2] + bvv[j]) * 0.125f;
                float v3 = (acc[j][3] + bvv[j]) * 0.125f;
                vfrag[j] = short8{(short)f2bf(v0), (short)f2bf(v1),
                                  (short)f2bf(v2), (short)f2bf(v3), 0, 0, 0, 0};
            }
            #pragma unroll
            for (int i = 0; i < 4; ++i)
                #pragma unroll
                for (int j = 0; j < 4; ++j)
                    kvacc[i][j] = __builtin_amdgcn_mfma_f32_16x16x32_bf16(
                        kfrag[i], vfrag[j], kvacc[i][j], 0, 0, 0);
        }
        __builtin_amdgcn_sched_barrier(0);
    }

    __syncthreads();   // all W_s/qbuf use done -> overlay region free

    // ---- cross-wave reduce in 2 halves (32 d-rows each), then atomics ----
    #pragma unroll
    for (int half = 0; half < 2; ++half) {
        #pragma unroll
        for (int i2 = 0; i2 < 2; ++i2) {
            const int ii = half * 2 + i2;
            #pragma unroll
            for (int j = 0; j < 4; ++j)
                #pragma unroll
                for (int r = 0; r < 4; ++r)
                    kvred[w * 2112 + (i2 * 16 + qd * 4 + r) * 66 + j * 16 + lq] =
                        kvacc[ii][j][r];
        }
        if (half == 0 && qd == 0) {
            #pragma unroll
            for (int j = 0; j < 4; ++j) sred[w * 64 + j * 16 + lq] = sacc[j];
        }
        __syncthreads();
        for (int idx = t; idx < 2048; idx += 256) {
            int dl = idx >> 6, e = idx & 63;
            float s = kvred[dl * 66 + e] + kvred[2112 + dl * 66 + e]
                    + kvred[2 * 2112 + dl * 66 + e] + kvred[3 * 2112 + dl * 66 + e];
            atomicAdd(&kvraw[bh * 4096 + (half * 32 + dl) * 64 + e], s);
        }
        if (half == 1 && t < 64) {
            float s = sred[t] + sred[64 + t] + sred[128 + t] + sred[192 + t];
            atomicAdd(&Sg[bh * 64 + t], s);
        }
        if (half == 0) __syncthreads();
    }
}

// ---------------------------------------------------------------------------
// Kernel 2: KWT[b][c][h*64+d] = sum_e (kvraw[bh][d][e]/S[d]) * Wp[c][h*64+e]
// ---------------------------------------------------------------------------
__global__ __launch_bounds__(256) void kw_kernel(
    const float* __restrict__ kvraw, const float* __restrict__ Sg,
    const float* __restrict__ Wp, unsigned short* __restrict__ KWT)
{
    __shared__ float kv_s[64 * 68];   // [e][d]
    __shared__ float w_s[64 * 68];    // [e][c]
    __shared__ float rS_s[64];
    const int bh = blockIdx.x / (C / 64);
    const int ct = blockIdx.x % (C / 64);
    const int b = bh / H, h = bh % H;
    const int c0 = ct * 64;
    const int t = threadIdx.x, dg = t >> 4, cg = t & 15;

    if (t < 64) rS_s[t] = 1.f / Sg[bh * 64 + t];
    __syncthreads();

    for (int i = t; i < 4096; i += 256) {
        int row = i >> 6, e = i & 63;
        kv_s[e * 68 + row] = kvraw[bh * (D * D) + row * 64 + e] * rS_s[row];
        w_s[e * 68 + row]  = Wp[(size_t)(c0 + row) * C + h * 64 + e];
    }
    __syncthreads();

    float acc[4][4] = {};
    for (int e = 0; e < 64; ++e) {
        float4 a = *(float4*)&kv_s[e * 68 + dg * 4];
        float4 w = *(float4*)&w_s[e * 68 + cg * 4];
        const float a4[4] = {a.x, a.y, a.z, a.w};
        const float w4[4] = {w.x, w.y, w.z, w.w};
        #pragma unroll
        for (int i = 0; i < 4; ++i)
            #pragma unroll
            for (int j = 0; j < 4; ++j) acc[i][j] += a4[i] * w4[j];
    }
    #pragma unroll
    for (int i = 0; i < 4; ++i)
        #pragma unroll
        for (int j = 0; j < 4; ++j) {
            int d = dg * 4 + i, c = c0 + cg * 4 + j;
            KWT[((size_t)b * C + c) * (H * D) + h * 64 + d] = f2bf(acc[i][j]);
        }
}

// ---------------------------------------------------------------------------
// Kernel 3 (MFMA): out[m][c] = sum_k q[m][k] * KWT[c][k] + bp[c]
// ---------------------------------------------------------------------------
__global__ __launch_bounds__(256) void out_gemm(
    const unsigned short* __restrict__ q, const unsigned short* __restrict__ KWT,
    const float* __restrict__ bp, float* __restrict__ out)
{
    __shared__ __align__(16) unsigned short A_s[128 * 72];
    __shared__ __align__(16) unsigned short B_s[128 * 72];

    const int mt = blockIdx.x / (C / 128);
    const int ct = blockIdx.x % (C / 128);
    const int m0 = mt * 128, c0 = ct * 128;
    const int b  = m0 >> 13;
    const int n0 = m0 & (N - 1);
    const int t  = threadIdx.x;
    const int lane = t & 63;
    const int w  = t >> 6;
    const int wm = w >> 1, wn = w & 1;
    const int lq = lane & 15;
    const int qd = lane >> 4;

    f32x4 acc[4][4] = {};

    for (int h = 0; h < H; ++h) {
        if (h) __syncthreads();
        const unsigned short* qb = q + (size_t)(b * H + h) * N * D + (size_t)n0 * D;
        const unsigned short* kb = KWT + ((size_t)b * C + c0) * (H * D) + h * 64;
        #pragma unroll
        for (int it = 0; it < 4; ++it) {
            int id = it * 256 + t;
            int r = id >> 3, c8 = id & 7;
            *(uint4*)&A_s[r * 72 + c8 * 8] = *(const uint4*)(qb + r * 64 + c8 * 8);
            *(uint4*)&B_s[r * 72 + c8 * 8] = *(const uint4*)(kb + (size_t)r * (H * D) + c8 * 8);
        }
        __syncthreads();

        #pragma unroll
        for (int kk = 0; kk < 64; kk += 32) {
            short8 af[4], bf[4];
            #pragma unroll
            for (int i = 0; i < 4; ++i)
                af[i] = *(short8*)&A_s[(wm * 64 + i * 16 + lq) * 72 + kk + qd * 8];
            #pragma unroll
            for (int j = 0; j < 4; ++j)
                bf[j] = *(short8*)&B_s[(wn * 64 + j * 16 + lq) * 72 + kk + qd * 8];
            #pragma unroll
            for (int i = 0; i < 4; ++i)
                #pragma unroll
                for (int j = 0; j < 4; ++j)
                    acc[i][j] = __builtin_amdgcn_mfma_f32_16x16x32_bf16(
                        af[i], bf[j], acc[i][j], 0, 0, 0);
        }
    }

    float bpv[4];
    #pragma unroll
    for (int j = 0; j < 4; ++j) bpv[j] = bp[c0 + wn * 64 + j * 16 + lq];

    #pragma unroll
    for (int i = 0; i < 4; ++i) {
        #pragma unroll
        for (int r = 0; r < 4; ++r) {
            size_t row = (size_t)m0 + wm * 64 + i * 16 + qd * 4 + r;
            float* orow = out + row * C + c0 + wn * 64;
            #pragma unroll
            for (int j = 0; j < 4; ++j)
                orow[j * 16 + lq] = acc[i][j][r] + bpv[j];
        }
    }
}

// ---------------------------------------------------------------------------
extern "C" void kernel_launch(void* const* d_in, const int* in_sizes, int n_in,
                              void* d_out, int out_size, void* d_ws, size_t ws_size,
                              hipStream_t stream)
{
    const float* x  = (const float*)d_in[0];
    const float* Wq = (const float*)d_in[1];
    const float* bq = (const float*)d_in[2];
    const float* Wk = (const float*)d_in[3];
    const float* bk = (const float*)d_in[4];
    const float* Wv = (const float*)d_in[5];
    const float* bv = (const float*)d_in[6];
    const float* Wp = (const float*)d_in[7];
    const float* bp = (const float*)d_in[8];
    float* out = (float*)d_out;

    const size_t SZ = (size_t)B * H * N * D;
    float* ws   = (float*)d_ws;
    unsigned short* q = (unsigned short*)ws;          // [BH, N, D] bf16
    float* kvraw = ws + SZ;                           // [BH, 64, 64] fp32
    float* Sg    = kvraw + (size_t)BH * D * D;        // [BH, 64] fp32
    unsigned short* KWT = (unsigned short*)(Sg + BH * 64);   // [B, C, H*D] bf16
    unsigned short* Wt  = KWT + (size_t)B * C * (H * D);     // [3,H,64,64] bf16

    wprep<<<3 * H, 64, 0, stream>>>(Wq, Wk, Wv, Wt);
    hipMemsetAsync(kvraw, 0, ((size_t)BH * D * D + BH * 64) * sizeof(float), stream);
    proj_kernel<<<BH * (N / 256), 256, 0, stream>>>(x, Wt, bq, bk, bv,
                                                    q, kvraw, Sg);
    kw_kernel<<<BH * (C / 64), 256, 0, stream>>>(kvraw, Sg, Wp, KWT);
    out_gemm<<<(BN / 128) * (C / 128), 256, 0, stream>>>(q, KWT, bp, out);
}